// Round 7
// baseline (307.892 us; speedup 1.0000x reference)
//
#include <hip/hip_runtime.h>
#include <hip/hip_bf16.h>

// Cross-attention B=8, S_ENC=2048, S_DEC=1024, D=512, U=512.
// R7: replace softmax+PV with stats (row m, 1/l) + BARRIER-FREE PV:
//  - PV has no LDS, no __syncthreads: each lane loads its MFMA fragments
//    directly from global (S fp32 -> exp2 in regs -> fp16 A-frag; vt fp16
//    B-frag contiguous 16 B). Compiler pipelines loads across K (no vmcnt(0)
//    drain). P (67 MB round-trip) never materialized.
//  - LDS-staged K-loops capped at 10-13% MfmaUtil in R3/R4/R6 (barrier drain).
// Projections/score unchanged (R4/R6 best configs). Converts merged.
//
// ws: qh [0,8M) | kh [8M,24M) | vt [32M,48M) | S [48M,112M) fp32 |
//     dech @48M (dead pre-S) | Wt @56M (dead pre-S) | ench @112M (dead pre-stats)
//     m_ @112M (32KB) | linv_ @112M+32K

typedef __attribute__((ext_vector_type(8))) _Float16 f16x8;
typedef __attribute__((ext_vector_type(4))) _Float16 f16x4;
typedef __attribute__((ext_vector_type(4))) float f32x4;

#define MFMA16(a, b, c) __builtin_amdgcn_mfma_f32_16x16x32_f16(a, b, c, 0, 0, 0)
#define L2E 1.44269504088896f

__device__ __forceinline__ void glds16(const void* g, void* l) {
    __builtin_amdgcn_global_load_lds(
        (const __attribute__((address_space(1))) void*)g,
        (__attribute__((address_space(3))) void*)l, 16, 0, 0);
}

// enc+dec fp32 -> fp16 in one launch. 8 elems/thread.
__global__ __launch_bounds__(256) void convert_all(const float* __restrict__ enc,
                                                   const float* __restrict__ dec,
                                                   _Float16* __restrict__ oenc,
                                                   _Float16* __restrict__ odec) {
    const int b = blockIdx.x;
    const float* x;
    _Float16* o;
    size_t i;
    if (b < 4096) { x = enc; o = oenc; i = ((size_t)b * 256 + threadIdx.x) * 8; }
    else          { x = dec; o = odec; i = ((size_t)(b - 4096) * 256 + threadIdx.x) * 8; }
    float4 a0 = *(const float4*)(x + i);
    float4 a1 = *(const float4*)(x + i + 4);
    float v[8] = {a0.x, a0.y, a0.z, a0.w, a1.x, a1.y, a1.z, a1.w};
    f16x8 h;
#pragma unroll
    for (int j = 0; j < 8; ++j) h[j] = (_Float16)v[j];
    *(f16x8*)(o + i) = h;
}

// W[512][512] (z selects Wq/Wk/Wv) -> Wt fp16 plane [u][d].
__global__ __launch_bounds__(256) void wtrans_kernel(const float* __restrict__ Wq,
                                                     const float* __restrict__ Wk,
                                                     const float* __restrict__ Wv,
                                                     _Float16* __restrict__ planes) {
    const float* W = blockIdx.z == 0 ? Wq : (blockIdx.z == 1 ? Wk : Wv);
    _Float16* ot = planes + (size_t)blockIdx.z * 262144;
    __shared__ float T[64][65];
    const int d0 = blockIdx.y * 64, u0 = blockIdx.x * 64;
    const int tr = threadIdx.x >> 4, tc = (threadIdx.x & 15) * 4;
#pragma unroll
    for (int j = 0; j < 4; ++j) {
        float4 vv = *(const float4*)(W + (size_t)(d0 + tr + j * 16) * 512 + u0 + tc);
        T[tr + j * 16][tc + 0] = vv.x;
        T[tr + j * 16][tc + 1] = vv.y;
        T[tr + j * 16][tc + 2] = vv.z;
        T[tr + j * 16][tc + 3] = vv.w;
    }
    __syncthreads();
#pragma unroll
    for (int j = 0; j < 4; ++j) {
        int ul = tr + j * 16;
        f16x4 h;
#pragma unroll
        for (int i = 0; i < 4; ++i) h[i] = (_Float16)T[tc + i][ul];
        *(f16x4*)(ot + (size_t)(u0 + ul) * 512 + d0 + tc) = h;
    }
}

// BM x BN tile GEMM (fp16 in, fp32 accum), dbuf LDS, glds-16 staging.
// OUT: 0 = fp16 C, 1 = transposed fp16 vt[b][u][s] (128x128 only), 2 = fp32 C.
template <int BM, int BN, int OUT>
__global__ __launch_bounds__(256) void gemm_kernel(
    const _Float16* __restrict__ A, const _Float16* __restrict__ B,
    void* __restrict__ O1,
    int lda, int ldb, int K, int a_row_batch, long b_batch, int ldo) {
    constexpr int ASZ = BM * 64, BSZ = BN * 64;
    constexpr int BUFSZ = ASZ + BSZ;
    constexpr int MT = BM / 32, NT = BN / 32;
    constexpr int JA = BM / 64, JB = BN / 64;
    __shared__ __align__(16) char smem[2 * BUFSZ];

    const int tid = threadIdx.x;
    const int wave = tid >> 6, lane = tid & 63;
    const int quad = lane >> 4, m16 = lane & 15;
    const int wr = wave >> 1, wc = wave & 1;
    const int z = blockIdx.z;
    const int row0 = z * a_row_batch + blockIdx.y * BM;
    const int col0 = blockIdx.x * BN;

    const int srowA = wave * (16 * JA) + (lane >> 2);
    const int srowB = wave * (16 * JB) + (lane >> 2);
    const int scol = (lane & 3) * 8;
    const _Float16* agp = A + (size_t)(row0 + srowA) * lda + scol;
    const _Float16* bgp = B + (size_t)z * b_batch + (size_t)(col0 + srowB) * ldb + scol;
    const int ldsAoff = wave * (1024 * JA);
    const int ldsBoff = ASZ + wave * (1024 * JB);

    f32x4 acc[MT][NT];
#pragma unroll
    for (int mt = 0; mt < MT; ++mt)
#pragma unroll
        for (int nt = 0; nt < NT; ++nt) acc[mt][nt] = (f32x4){0.f, 0.f, 0.f, 0.f};

    const int nIter = K / 32;
    auto stage = [&](int i, int buf) {
        char* base = smem + buf * BUFSZ;
        const int k0 = i * 32;
#pragma unroll
        for (int j = 0; j < JA; ++j)
            glds16(agp + k0 + j * 16 * lda, base + ldsAoff + j * 1024);
#pragma unroll
        for (int j = 0; j < JB; ++j)
            glds16(bgp + k0 + j * 16 * ldb, base + ldsBoff + j * 1024);
    };

    stage(0, 0);
    for (int i = 0; i < nIter; ++i) {
        __syncthreads();
        if (i + 1 < nIter) stage(i + 1, (i + 1) & 1);
        const char* bb = smem + (i & 1) * BUFSZ;
        const char* pa = bb + (wr * (BM / 2) + m16) * 64 + quad * 16;
        const char* pb = bb + ASZ + (wc * (BN / 2) + m16) * 64 + quad * 16;
        f16x8 af[MT];
#pragma unroll
        for (int mt = 0; mt < MT; ++mt) af[mt] = *(const f16x8*)(pa + mt * 1024);
#pragma unroll
        for (int nt = 0; nt < NT; ++nt) {
            f16x8 bf = *(const f16x8*)(pb + nt * 1024);
#pragma unroll
            for (int mt = 0; mt < MT; ++mt) acc[mt][nt] = MFMA16(af[mt], bf, acc[mt][nt]);
        }
    }

    if (OUT == 0) {
        _Float16* o = (_Float16*)O1;
#pragma unroll
        for (int mt = 0; mt < MT; ++mt)
#pragma unroll
            for (int nt = 0; nt < NT; ++nt)
#pragma unroll
                for (int rr = 0; rr < 4; ++rr) {
                    int row = row0 + wr * (BM / 2) + mt * 16 + quad * 4 + rr;
                    int col = col0 + wc * (BN / 2) + nt * 16 + m16;
                    o[(size_t)row * ldo + col] = (_Float16)acc[mt][nt][rr];
                }
    } else if (OUT == 2) {
        float* o = (float*)O1;
#pragma unroll
        for (int mt = 0; mt < MT; ++mt)
#pragma unroll
            for (int nt = 0; nt < NT; ++nt)
#pragma unroll
                for (int rr = 0; rr < 4; ++rr) {
                    int row = row0 + wr * (BM / 2) + mt * 16 + quad * 4 + rr;
                    int col = col0 + wc * (BN / 2) + nt * 16 + m16;
                    o[(size_t)row * ldo + col] = acc[mt][nt][rr];
                }
    } else {
        _Float16* vtp = (_Float16*)O1;
        const int row0g = blockIdx.y * 128;
        const int b = row0g >> 11;
        const int s_base = (row0g & 2047) + wr * 64;
        char* reg = smem + wave * 4096;
#pragma unroll
        for (int p = 0; p < 2; ++p) {
            __syncthreads();
#pragma unroll
            for (int nt2 = 0; nt2 < 2; ++nt2) {
                int nt = p * 2 + nt2;
#pragma unroll
                for (int mt = 0; mt < 4; ++mt) {
                    f16x4 pk;
#pragma unroll
                    for (int rr = 0; rr < 4; ++rr) pk[rr] = (_Float16)acc[mt][nt][rr];
                    *(f16x4*)(reg + (nt2 * 16 + m16) * 128 + (mt * 16 + quad * 4) * 2) = pk;
                }
            }
            __syncthreads();
            const int u_base = col0 + wc * 64 + p * 32;
#pragma unroll
            for (int j = 0; j < 4; ++j) {
                int n = j * 8 + (lane >> 3);
                int mo = (lane & 7) * 8;
                f16x8 val = *(const f16x8*)(reg + n * 128 + mo * 2);
                *(f16x8*)(vtp + (size_t)(b * 512 + u_base + n) * 2048 + s_base + mo) = val;
            }
        }
    }
}

// Row stats over 2048 cols: m_[row] = max, linv_[row] = 1/sum(exp2((s-m)*L2E)).
__global__ __launch_bounds__(256) void stats_kernel(const float* __restrict__ S,
                                                    float* __restrict__ m_,
                                                    float* __restrict__ linv_) {
    const int row = blockIdx.x;
    const int tid = threadIdx.x;
    const int wave = tid >> 6, lane = tid & 63;
    __shared__ float red[8];

    const float* sp = S + (size_t)row * 2048 + tid * 8;
    float4 x0 = *(const float4*)sp;
    float4 x1 = *(const float4*)(sp + 4);
    float v[8] = {x0.x, x0.y, x0.z, x0.w, x1.x, x1.y, x1.z, x1.w};

    float mx = v[0];
#pragma unroll
    for (int i = 1; i < 8; ++i) mx = fmaxf(mx, v[i]);
#pragma unroll
    for (int off = 32; off > 0; off >>= 1) mx = fmaxf(mx, __shfl_down(mx, off));
    if (lane == 0) red[wave] = mx;
    __syncthreads();
    if (tid == 0) red[4] = fmaxf(fmaxf(red[0], red[1]), fmaxf(red[2], red[3]));
    __syncthreads();
    mx = red[4];

    float sum = 0.f;
#pragma unroll
    for (int i = 0; i < 8; ++i) sum += exp2f((v[i] - mx) * L2E);
#pragma unroll
    for (int off = 32; off > 0; off >>= 1) sum += __shfl_down(sum, off);
    if (lane == 0) red[wave] = sum;
    __syncthreads();
    if (tid == 0) {
        m_[row] = mx;
        linv_[row] = 1.0f / (red[0] + red[1] + red[2] + red[3]);
    }
}

// Barrier-free PV: out[q][u] = (exp(S[q]-m)/l) . V. One wave per 32x64 tile.
// A-frags: S fp32 read per-lane from global, exp2 in regs, cvt fp16.
// B-frags: vt fp16, 16 B contiguous per lane. No LDS, no __syncthreads.
__global__ __launch_bounds__(256) void pv_kernel(
    const float* __restrict__ S, const _Float16* __restrict__ vt,
    const float* __restrict__ m_, const float* __restrict__ linv_,
    float* __restrict__ out) {
    const int wid = blockIdx.x * 4 + (threadIdx.x >> 6);
    const int lane = threadIdx.x & 63;
    const int quad = lane >> 4, m16 = lane & 15;
    const int ntile = wid & 7;   // 8 n-tiles of 64 cols
    const int mtile = wid >> 3;  // 256 m-tiles of 32 rows
    const int row0 = mtile * 32;
    const int z = row0 >> 10;
    const int u0 = ntile * 64;

    const float* srow[2];
    float mrow[2];
#pragma unroll
    for (int mf = 0; mf < 2; ++mf) {
        srow[mf] = S + (size_t)(row0 + mf * 16 + m16) * 2048 + quad * 8;
        mrow[mf] = m_[row0 + mf * 16 + m16];
    }
    const _Float16* vrow[4];
#pragma unroll
    for (int nf = 0; nf < 4; ++nf)
        vrow[nf] = vt + (size_t)(z * 512 + u0 + nf * 16 + m16) * 2048 + quad * 8;

    f32x4 acc[2][4];
#pragma unroll
    for (int mf = 0; mf < 2; ++mf)
#pragma unroll
        for (int nf = 0; nf < 4; ++nf) acc[mf][nf] = (f32x4){0.f, 0.f, 0.f, 0.f};

    float4 Ab[2][2][2];  // [buf][mf][half]
    f16x8 Bb[2][4];      // [buf][nf]
#pragma unroll
    for (int mf = 0; mf < 2; ++mf) {
        Ab[0][mf][0] = *(const float4*)(srow[mf]);
        Ab[0][mf][1] = *(const float4*)(srow[mf] + 4);
    }
#pragma unroll
    for (int nf = 0; nf < 4; ++nf) Bb[0][nf] = *(const f16x8*)(vrow[nf]);

#pragma unroll 2
    for (int i = 0; i < 64; ++i) {
        const int cur = i & 1, nxt = cur ^ 1;
        if (i + 1 < 64) {
            const int k = (i + 1) * 32;
#pragma unroll
            for (int mf = 0; mf < 2; ++mf) {
                Ab[nxt][mf][0] = *(const float4*)(srow[mf] + k);
                Ab[nxt][mf][1] = *(const float4*)(srow[mf] + k + 4);
            }
#pragma unroll
            for (int nf = 0; nf < 4; ++nf) Bb[nxt][nf] = *(const f16x8*)(vrow[nf] + k);
        }
        f16x8 a16[2];
#pragma unroll
        for (int mf = 0; mf < 2; ++mf) {
#pragma unroll
            for (int j = 0; j < 4; ++j) {
                a16[mf][j] = (_Float16)exp2f((Ab[cur][mf][0][j] - mrow[mf]) * L2E);
                a16[mf][j + 4] = (_Float16)exp2f((Ab[cur][mf][1][j] - mrow[mf]) * L2E);
            }
        }
#pragma unroll
        for (int nf = 0; nf < 4; ++nf)
#pragma unroll
            for (int mf = 0; mf < 2; ++mf)
                acc[mf][nf] = MFMA16(a16[mf], Bb[cur][nf], acc[mf][nf]);
    }

#pragma unroll
    for (int mf = 0; mf < 2; ++mf)
#pragma unroll
        for (int rr = 0; rr < 4; ++rr) {
            const int grow = row0 + mf * 16 + quad * 4 + rr;
            const float li = linv_[grow];
#pragma unroll
            for (int nf = 0; nf < 4; ++nf)
                out[(size_t)grow * 512 + u0 + nf * 16 + m16] = acc[mf][nf][rr] * li;
        }
}

extern "C" void kernel_launch(void* const* d_in, const int* in_sizes, int n_in,
                              void* d_out, int out_size, void* d_ws, size_t ws_size,
                              hipStream_t stream) {
    const float* enc = (const float*)d_in[0];  // [8,2048,512]
    const float* dec = (const float*)d_in[1];  // [8,1024,512]
    const float* Wq = (const float*)d_in[2];   // [512,512]
    const float* Wk = (const float*)d_in[3];
    const float* Wv = (const float*)d_in[4];
    float* out = (float*)d_out;                // [8,1024,512] fp32

    char* ws = (char*)d_ws;
    _Float16* qh = (_Float16*)(ws);
    _Float16* kh = (_Float16*)(ws + ((size_t)8 << 20));
    _Float16* vt = (_Float16*)(ws + ((size_t)32 << 20));
    float* S = (float*)(ws + ((size_t)48 << 20));
    _Float16* dech = (_Float16*)(ws + ((size_t)48 << 20));  // dead before S written
    _Float16* wts = (_Float16*)(ws + ((size_t)56 << 20));   // dead before S written
    _Float16* ench = (_Float16*)(ws + ((size_t)112 << 20)); // dead before stats
    float* m_ = (float*)(ws + ((size_t)112 << 20));
    float* linv_ = (float*)(ws + ((size_t)112 << 20) + 32768);

    dim3 blk(256);
    convert_all<<<6144, blk, 0, stream>>>(enc, dec, ench, dech);
    wtrans_kernel<<<dim3(8, 8, 3), blk, 0, stream>>>(Wq, Wk, Wv, wts);
    // Projections
    gemm_kernel<64, 128, 0><<<dim3(4, 128, 1), blk, 0, stream>>>(
        dech, wts, qh, 512, 512, 512, 0, 0, 512);
    gemm_kernel<64, 128, 0><<<dim3(4, 256, 1), blk, 0, stream>>>(
        ench, wts + 262144, kh, 512, 512, 512, 0, 0, 512);
    gemm_kernel<128, 128, 1><<<dim3(4, 128, 1), blk, 0, stream>>>(
        ench, wts + 524288, vt, 512, 512, 512, 0, 0, 0);
    // Score: S[b,q,s] = q . k^T
    gemm_kernel<128, 128, 2><<<dim3(16, 8, 8), blk, 0, stream>>>(
        qh, kh, S, 512, 512, 512, 1024, (long)2048 * 512, 2048);
    // Row stats (m, 1/l)
    stats_kernel<<<8192, blk, 0, stream>>>(S, m_, linv_);
    // Barrier-free PV (2048 wave-tiles, 512 blocks)
    pv_kernel<<<512, blk, 0, stream>>>(S, vt, m_, linv_, out);
}

// Round 8
// 267.276 us; speedup vs baseline: 1.1520x; 1.1520x over previous
//
#include <hip/hip_runtime.h>
#include <hip/hip_bf16.h>

// Cross-attention B=8, S_ENC=2048, S_DEC=1024, D=512, U=512.
// R8: (a) PV = barrier-free direct-global fragment kernel over P fp16
// (R7 skeleton minus the exp chain that made it latency-bound);
// (b) launch count 8->5 (~10us gap per launch measured across rounds):
// prep = converts+Wtrans, proj = q+k+v in one kernel.
//
// ws: qh [0,8M) | kh [8M,24M) | P [0,32M) (after score) | vt [32M,48M) |
//     S [48M,112M) fp32 | dech @48M (dead pre-S) | Wt @56M (dead pre-S) |
//     ench @112M (dead after proj)

typedef __attribute__((ext_vector_type(8))) _Float16 f16x8;
typedef __attribute__((ext_vector_type(4))) _Float16 f16x4;
typedef __attribute__((ext_vector_type(4))) float f32x4;

#define MFMA16(a, b, c) __builtin_amdgcn_mfma_f32_16x16x32_f16(a, b, c, 0, 0, 0)
#define L2E 1.44269504088896f

__device__ __forceinline__ void glds16(const void* g, void* l) {
    __builtin_amdgcn_global_load_lds(
        (const __attribute__((address_space(1))) void*)g,
        (__attribute__((address_space(3))) void*)l, 16, 0, 0);
}

// prep: blocks [0,4096) enc cvt, [4096,6144) dec cvt, [6144,6336) W transpose.
__global__ __launch_bounds__(256) void prep_kernel(
    const float* __restrict__ enc, const float* __restrict__ dec,
    const float* __restrict__ Wq, const float* __restrict__ Wk,
    const float* __restrict__ Wv, _Float16* __restrict__ oenc,
    _Float16* __restrict__ odec, _Float16* __restrict__ planes) {
    const int bid = blockIdx.x;
    if (bid < 6144) {
        const float* x;
        _Float16* o;
        size_t i;
        if (bid < 4096) { x = enc; o = oenc; i = ((size_t)bid * 256 + threadIdx.x) * 8; }
        else { x = dec; o = odec; i = ((size_t)(bid - 4096) * 256 + threadIdx.x) * 8; }
        float4 a0 = *(const float4*)(x + i);
        float4 a1 = *(const float4*)(x + i + 4);
        float v[8] = {a0.x, a0.y, a0.z, a0.w, a1.x, a1.y, a1.z, a1.w};
        f16x8 h;
#pragma unroll
        for (int j = 0; j < 8; ++j) h[j] = (_Float16)v[j];
        *(f16x8*)(o + i) = h;
        return;
    }
    const int t = bid - 6144;
    const int zw = t >> 6, r = t & 63;
    const int u0 = (r & 7) * 64, d0 = (r >> 3) * 64;
    const float* W = zw == 0 ? Wq : (zw == 1 ? Wk : Wv);
    _Float16* ot = planes + (size_t)zw * 262144;
    __shared__ float T[64][65];
    const int tr = threadIdx.x >> 4, tc = (threadIdx.x & 15) * 4;
#pragma unroll
    for (int j = 0; j < 4; ++j) {
        float4 vv = *(const float4*)(W + (size_t)(d0 + tr + j * 16) * 512 + u0 + tc);
        T[tr + j * 16][tc + 0] = vv.x;
        T[tr + j * 16][tc + 1] = vv.y;
        T[tr + j * 16][tc + 2] = vv.z;
        T[tr + j * 16][tc + 3] = vv.w;
    }
    __syncthreads();
#pragma unroll
    for (int j = 0; j < 4; ++j) {
        int ul = tr + j * 16;
        f16x4 h;
#pragma unroll
        for (int i = 0; i < 4; ++i) h[i] = (_Float16)T[tc + i][ul];
        *(f16x4*)(ot + (size_t)(u0 + ul) * 512 + d0 + tc) = h;
    }
}

// Unified projections: one launch. 64x128 tiles, K=512, dbuf LDS, glds-16.
// Blocks [0,512): q = dech*Wq' -> qh ; [512,1536): k = ench*Wk' -> kh ;
// [1536,2560): v = ench*Wv' -> vt[b][u][s] (LDS-transpose epilogue).
__global__ __launch_bounds__(256) void proj_kernel(
    const _Float16* __restrict__ dech, const _Float16* __restrict__ ench,
    const _Float16* __restrict__ wts, _Float16* __restrict__ qh,
    _Float16* __restrict__ kh, _Float16* __restrict__ vt) {
    __shared__ __align__(16) char smem[24576];  // 2 x (4K A + 8K B)
    const int bid = blockIdx.x;
    int seg, bx, by;
    if (bid < 512) { seg = 0; bx = bid & 3; by = bid >> 2; }
    else if (bid < 1536) { int t = bid - 512; seg = 1; bx = t & 3; by = t >> 2; }
    else { int t = bid - 1536; seg = 2; bx = t & 3; by = t >> 2; }
    const _Float16* A = seg == 0 ? dech : ench;
    const _Float16* Bp = wts + (size_t)seg * 262144;

    const int tid = threadIdx.x;
    const int wave = tid >> 6, lane = tid & 63;
    const int quad = lane >> 4, m16 = lane & 15;
    const int wr = wave >> 1, wc = wave & 1;
    const int row0 = by * 64, col0 = bx * 128;

    const int srowA = wave * 16 + (lane >> 2);
    const int srowB = wave * 32 + (lane >> 2);
    const int scol = (lane & 3) * 8;
    const _Float16* agp = A + (size_t)(row0 + srowA) * 512 + scol;
    const _Float16* bgp = Bp + (size_t)(col0 + srowB) * 512 + scol;
    const int ldsAoff = wave * 1024;
    const int ldsBoff = 4096 + wave * 2048;

    f32x4 acc[2][4];
#pragma unroll
    for (int mt = 0; mt < 2; ++mt)
#pragma unroll
        for (int nt = 0; nt < 4; ++nt) acc[mt][nt] = (f32x4){0.f, 0.f, 0.f, 0.f};

    auto stage = [&](int i, int buf) {
        char* base = smem + buf * 12288;
        const int k0 = i * 32;
        glds16(agp + k0, base + ldsAoff);
#pragma unroll
        for (int j = 0; j < 2; ++j)
            glds16(bgp + k0 + j * 16 * 512, base + ldsBoff + j * 1024);
    };

    stage(0, 0);
    for (int i = 0; i < 16; ++i) {
        __syncthreads();
        if (i + 1 < 16) stage(i + 1, (i + 1) & 1);
        const char* bb = smem + (i & 1) * 12288;
        const char* pa = bb + (wr * 32 + m16) * 64 + quad * 16;
        const char* pb = bb + 4096 + (wc * 64 + m16) * 64 + quad * 16;
        f16x8 af[2];
#pragma unroll
        for (int mt = 0; mt < 2; ++mt) af[mt] = *(const f16x8*)(pa + mt * 1024);
#pragma unroll
        for (int nt = 0; nt < 4; ++nt) {
            f16x8 bf = *(const f16x8*)(pb + nt * 1024);
#pragma unroll
            for (int mt = 0; mt < 2; ++mt) acc[mt][nt] = MFMA16(af[mt], bf, acc[mt][nt]);
        }
    }

    if (seg < 2) {
        _Float16* o = seg == 0 ? qh : kh;
#pragma unroll
        for (int mt = 0; mt < 2; ++mt)
#pragma unroll
            for (int nt = 0; nt < 4; ++nt)
#pragma unroll
                for (int rr = 0; rr < 4; ++rr) {
                    int row = row0 + wr * 32 + mt * 16 + quad * 4 + rr;
                    int col = col0 + wc * 64 + nt * 16 + m16;
                    o[(size_t)row * 512 + col] = (_Float16)acc[mt][nt][rr];
                }
    } else {
        // v: write C^T into vt[b][u][s]. Per-wave 4 KB LDS slab [64 u][32 s].
        __syncthreads();  // all waves done with K-loop buffers
        char* reg = smem + wave * 4096;
#pragma unroll
        for (int nt = 0; nt < 4; ++nt)
#pragma unroll
            for (int mt = 0; mt < 2; ++mt) {
                f16x4 pk;
#pragma unroll
                for (int rr = 0; rr < 4; ++rr) pk[rr] = (_Float16)acc[mt][nt][rr];
                *(f16x4*)(reg + (nt * 16 + m16) * 64 + (mt * 16 + quad * 4) * 2) = pk;
            }
        const int b = row0 >> 11;
        const int s_base = (row0 & 2047) + wr * 32;
        const int u_base = col0 + wc * 64;
#pragma unroll
        for (int j = 0; j < 4; ++j) {
            int n = j * 16 + (lane >> 2);
            int mo = (lane & 3) * 8;
            f16x8 val = *(const f16x8*)(reg + n * 64 + mo * 2);
            *(f16x8*)(vt + (size_t)(b * 512 + u_base + n) * 2048 + s_base + mo) = val;
        }
    }
}

// Score GEMM: 128x128 tiles, S[b,q,s] = q.k^T (fp16 in, fp32 out), dbuf LDS.
__global__ __launch_bounds__(256) void score_kernel(
    const _Float16* __restrict__ qh, const _Float16* __restrict__ kh,
    float* __restrict__ S) {
    __shared__ __align__(16) char smem[32768];
    const int tid = threadIdx.x;
    const int wave = tid >> 6, lane = tid & 63;
    const int quad = lane >> 4, m16 = lane & 15;
    const int wr = wave >> 1, wc = wave & 1;
    const int z = blockIdx.z;
    const int row0 = z * 1024 + blockIdx.y * 128;
    const int col0 = blockIdx.x * 128;

    const int srow = wave * 32 + (lane >> 2);
    const int scol = (lane & 3) * 8;
    const _Float16* agp = qh + (size_t)(row0 + srow) * 512 + scol;
    const _Float16* bgp = kh + (size_t)(z * 2048 + col0 + srow) * 512 + scol;
    const int ldsAoff = wave * 2048;
    const int ldsBoff = 8192 + wave * 2048;

    f32x4 acc[4][4];
#pragma unroll
    for (int mt = 0; mt < 4; ++mt)
#pragma unroll
        for (int nt = 0; nt < 4; ++nt) acc[mt][nt] = (f32x4){0.f, 0.f, 0.f, 0.f};

    auto stage = [&](int i, int buf) {
        char* base = smem + buf * 16384;
        const int k0 = i * 32;
#pragma unroll
        for (int j = 0; j < 2; ++j) {
            glds16(agp + k0 + j * 16 * 512, base + ldsAoff + j * 1024);
            glds16(bgp + k0 + j * 16 * 512, base + ldsBoff + j * 1024);
        }
    };

    stage(0, 0);
    for (int i = 0; i < 16; ++i) {
        __syncthreads();
        if (i + 1 < 16) stage(i + 1, (i + 1) & 1);
        const char* bb = smem + (i & 1) * 16384;
        const char* pa = bb + (wr * 64 + m16) * 64 + quad * 16;
        const char* pb = bb + 8192 + (wc * 64 + m16) * 64 + quad * 16;
        f16x8 af[4];
#pragma unroll
        for (int mt = 0; mt < 4; ++mt) af[mt] = *(const f16x8*)(pa + mt * 1024);
#pragma unroll
        for (int nt = 0; nt < 4; ++nt) {
            f16x8 bf = *(const f16x8*)(pb + nt * 1024);
#pragma unroll
            for (int mt = 0; mt < 4; ++mt) acc[mt][nt] = MFMA16(af[mt], bf, acc[mt][nt]);
        }
    }
#pragma unroll
    for (int mt = 0; mt < 4; ++mt)
#pragma unroll
        for (int nt = 0; nt < 4; ++nt)
#pragma unroll
            for (int rr = 0; rr < 4; ++rr) {
                int row = row0 + wr * 64 + mt * 16 + quad * 4 + rr;
                int col = col0 + wc * 64 + nt * 16 + m16;
                S[(size_t)row * 2048 + col] = acc[mt][nt][rr];
            }
}

// Row softmax over 2048 cols, fp32 in -> fp16 out (normalized). One block/row.
__global__ __launch_bounds__(256) void softmax_kernel(const float* __restrict__ S,
                                                      _Float16* __restrict__ P) {
    const int row = blockIdx.x;
    const int tid = threadIdx.x;
    const int wave = tid >> 6, lane = tid & 63;
    __shared__ float red[8];

    const float* sp = S + (size_t)row * 2048 + tid * 8;
    float4 x0 = *(const float4*)sp;
    float4 x1 = *(const float4*)(sp + 4);
    float v[8] = {x0.x, x0.y, x0.z, x0.w, x1.x, x1.y, x1.z, x1.w};

    float mx = v[0];
#pragma unroll
    for (int i = 1; i < 8; ++i) mx = fmaxf(mx, v[i]);
#pragma unroll
    for (int off = 32; off > 0; off >>= 1) mx = fmaxf(mx, __shfl_down(mx, off));
    if (lane == 0) red[wave] = mx;
    __syncthreads();
    if (tid == 0) red[4] = fmaxf(fmaxf(red[0], red[1]), fmaxf(red[2], red[3]));
    __syncthreads();
    mx = red[4];

    float e[8];
    float sum = 0.f;
#pragma unroll
    for (int i = 0; i < 8; ++i) {
        e[i] = exp2f((v[i] - mx) * L2E);
        sum += e[i];
    }
#pragma unroll
    for (int off = 32; off > 0; off >>= 1) sum += __shfl_down(sum, off);
    if (lane == 0) red[wave] = sum;
    __syncthreads();
    if (tid == 0) red[5] = red[0] + red[1] + red[2] + red[3];
    __syncthreads();
    float inv = 1.0f / red[5];

    f16x8 ov;
#pragma unroll
    for (int i = 0; i < 8; ++i) ov[i] = (_Float16)(e[i] * inv);
    *(f16x8*)(P + (size_t)row * 2048 + tid * 8) = ov;
}

// Barrier-free PV: out = P . V^T(vt). One wave per 32x64 tile; no LDS, no
// __syncthreads. A/B fragments loaded per-lane from global (L2-resident),
// reg double-buffered; pure load->MFMA chain.
__global__ __launch_bounds__(256) void pv_kernel(
    const _Float16* __restrict__ P, const _Float16* __restrict__ vt,
    float* __restrict__ out) {
    const int wid = blockIdx.x * 4 + (threadIdx.x >> 6);
    const int lane = threadIdx.x & 63;
    const int quad = lane >> 4, m16 = lane & 15;
    const int ntile = wid & 7;   // 8 u-tiles of 64
    const int mtile = wid >> 3;  // 256 q-tiles of 32
    const int row0 = mtile * 32;
    const int z = row0 >> 10;
    const int u0 = ntile * 64;

    const _Float16* prow[2];
#pragma unroll
    for (int mf = 0; mf < 2; ++mf)
        prow[mf] = P + (size_t)(row0 + mf * 16 + m16) * 2048 + quad * 8;
    const _Float16* vrow[4];
#pragma unroll
    for (int nf = 0; nf < 4; ++nf)
        vrow[nf] = vt + (size_t)(z * 512 + u0 + nf * 16 + m16) * 2048 + quad * 8;

    f32x4 acc[2][4];
#pragma unroll
    for (int mf = 0; mf < 2; ++mf)
#pragma unroll
        for (int nf = 0; nf < 4; ++nf) acc[mf][nf] = (f32x4){0.f, 0.f, 0.f, 0.f};

    f16x8 Ab[2][2], Bb[2][4];
#pragma unroll
    for (int mf = 0; mf < 2; ++mf) Ab[0][mf] = *(const f16x8*)(prow[mf]);
#pragma unroll
    for (int nf = 0; nf < 4; ++nf) Bb[0][nf] = *(const f16x8*)(vrow[nf]);

#pragma unroll 4
    for (int i = 0; i < 64; ++i) {
        const int cur = i & 1, nxt = cur ^ 1;
        if (i + 1 < 64) {
            const int k = (i + 1) * 32;
#pragma unroll
            for (int mf = 0; mf < 2; ++mf) Ab[nxt][mf] = *(const f16x8*)(prow[mf] + k);
#pragma unroll
            for (int nf = 0; nf < 4; ++nf) Bb[nxt][nf] = *(const f16x8*)(vrow[nf] + k);
        }
#pragma unroll
        for (int nf = 0; nf < 4; ++nf)
#pragma unroll
            for (int mf = 0; mf < 2; ++mf)
                acc[mf][nf] = MFMA16(Ab[cur][mf], Bb[cur][nf], acc[mf][nf]);
    }

#pragma unroll
    for (int mf = 0; mf < 2; ++mf)
#pragma unroll
        for (int rr = 0; rr < 4; ++rr) {
            const int grow = row0 + mf * 16 + quad * 4 + rr;
#pragma unroll
            for (int nf = 0; nf < 4; ++nf)
                out[(size_t)grow * 512 + u0 + nf * 16 + m16] = acc[mf][nf][rr];
        }
}

extern "C" void kernel_launch(void* const* d_in, const int* in_sizes, int n_in,
                              void* d_out, int out_size, void* d_ws, size_t ws_size,
                              hipStream_t stream) {
    const float* enc = (const float*)d_in[0];  // [8,2048,512]
    const float* dec = (const float*)d_in[1];  // [8,1024,512]
    const float* Wq = (const float*)d_in[2];   // [512,512]
    const float* Wk = (const float*)d_in[3];
    const float* Wv = (const float*)d_in[4];
    float* out = (float*)d_out;                // [8,1024,512] fp32

    char* ws = (char*)d_ws;
    _Float16* qh = (_Float16*)(ws);
    _Float16* kh = (_Float16*)(ws + ((size_t)8 << 20));
    _Float16* P = (_Float16*)(ws);                          // aliases qh/kh after score
    _Float16* vt = (_Float16*)(ws + ((size_t)32 << 20));
    float* S = (float*)(ws + ((size_t)48 << 20));
    _Float16* dech = (_Float16*)(ws + ((size_t)48 << 20));  // dead before S written
    _Float16* wts = (_Float16*)(ws + ((size_t)56 << 20));   // dead before S written
    _Float16* ench = (_Float16*)(ws + ((size_t)112 << 20)); // dead after proj

    dim3 blk(256);
    prep_kernel<<<6336, blk, 0, stream>>>(enc, dec, Wq, Wk, Wv, ench, dech, wts);
    proj_kernel<<<2560, blk, 0, stream>>>(dech, ench, wts, qh, kh, vt);
    score_kernel<<<dim3(16, 8, 8), blk, 0, stream>>>(qh, kh, S);
    softmax_kernel<<<8192, blk, 0, stream>>>(S, P);
    pv_kernel<<<512, blk, 0, stream>>>(P, vt, out);
}

// Round 9
// 206.932 us; speedup vs baseline: 1.4879x; 1.2916x over previous
//
#include <hip/hip_runtime.h>
#include <hip/hip_bf16.h>

// Cross-attention B=8, S_ENC=2048, S_DEC=1024, D=512, U=512.
// R9: batch-pinned XCD swizzle (z = blockIdx & 7) for score and PV.
// R8's PV was latency-bound on HBM (3400 cyc/iter, MfmaUtil 7%) because every
// XCD's working set was the full P+vt (48 MB >> 4 MB L2). Pinning batch z to
// XCD z makes the per-XCD set P[z] streamed + vt[z] (2 MB) resident.
// PV uses the proven R4 LDS-dbuf 64x128 GEMM body. 5 launches as R8.
//
// ws: qh [0,8M) | kh [8M,24M) | P [0,32M) (after score) | vt [32M,48M) |
//     S [48M,112M) fp32 | dech @48M (dead pre-S) | Wt @56M (dead pre-S) |
//     ench @112M (dead after proj)

typedef __attribute__((ext_vector_type(8))) _Float16 f16x8;
typedef __attribute__((ext_vector_type(4))) _Float16 f16x4;
typedef __attribute__((ext_vector_type(4))) float f32x4;

#define MFMA16(a, b, c) __builtin_amdgcn_mfma_f32_16x16x32_f16(a, b, c, 0, 0, 0)
#define L2E 1.44269504088896f

__device__ __forceinline__ void glds16(const void* g, void* l) {
    __builtin_amdgcn_global_load_lds(
        (const __attribute__((address_space(1))) void*)g,
        (__attribute__((address_space(3))) void*)l, 16, 0, 0);
}

// prep: blocks [0,4096) enc cvt, [4096,6144) dec cvt, [6144,6336) W transpose.
__global__ __launch_bounds__(256) void prep_kernel(
    const float* __restrict__ enc, const float* __restrict__ dec,
    const float* __restrict__ Wq, const float* __restrict__ Wk,
    const float* __restrict__ Wv, _Float16* __restrict__ oenc,
    _Float16* __restrict__ odec, _Float16* __restrict__ planes) {
    const int bid = blockIdx.x;
    if (bid < 6144) {
        const float* x;
        _Float16* o;
        size_t i;
        if (bid < 4096) { x = enc; o = oenc; i = ((size_t)bid * 256 + threadIdx.x) * 8; }
        else { x = dec; o = odec; i = ((size_t)(bid - 4096) * 256 + threadIdx.x) * 8; }
        float4 a0 = *(const float4*)(x + i);
        float4 a1 = *(const float4*)(x + i + 4);
        float v[8] = {a0.x, a0.y, a0.z, a0.w, a1.x, a1.y, a1.z, a1.w};
        f16x8 h;
#pragma unroll
        for (int j = 0; j < 8; ++j) h[j] = (_Float16)v[j];
        *(f16x8*)(o + i) = h;
        return;
    }
    const int t = bid - 6144;
    const int zw = t >> 6, r = t & 63;
    const int u0 = (r & 7) * 64, d0 = (r >> 3) * 64;
    const float* W = zw == 0 ? Wq : (zw == 1 ? Wk : Wv);
    _Float16* ot = planes + (size_t)zw * 262144;
    __shared__ float T[64][65];
    const int tr = threadIdx.x >> 4, tc = (threadIdx.x & 15) * 4;
#pragma unroll
    for (int j = 0; j < 4; ++j) {
        float4 vv = *(const float4*)(W + (size_t)(d0 + tr + j * 16) * 512 + u0 + tc);
        T[tr + j * 16][tc + 0] = vv.x;
        T[tr + j * 16][tc + 1] = vv.y;
        T[tr + j * 16][tc + 2] = vv.z;
        T[tr + j * 16][tc + 3] = vv.w;
    }
    __syncthreads();
#pragma unroll
    for (int j = 0; j < 4; ++j) {
        int ul = tr + j * 16;
        f16x4 h;
#pragma unroll
        for (int i = 0; i < 4; ++i) h[i] = (_Float16)T[tc + i][ul];
        *(f16x4*)(ot + (size_t)(u0 + ul) * 512 + d0 + tc) = h;
    }
}

// Unified projections (R8): 64x128 tiles, K=512, dbuf LDS, glds-16.
__global__ __launch_bounds__(256) void proj_kernel(
    const _Float16* __restrict__ dech, const _Float16* __restrict__ ench,
    const _Float16* __restrict__ wts, _Float16* __restrict__ qh,
    _Float16* __restrict__ kh, _Float16* __restrict__ vt) {
    __shared__ __align__(16) char smem[24576];
    const int bid = blockIdx.x;
    int seg, bx, by;
    if (bid < 512) { seg = 0; bx = bid & 3; by = bid >> 2; }
    else if (bid < 1536) { int t = bid - 512; seg = 1; bx = t & 3; by = t >> 2; }
    else { int t = bid - 1536; seg = 2; bx = t & 3; by = t >> 2; }
    const _Float16* A = seg == 0 ? dech : ench;
    const _Float16* Bp = wts + (size_t)seg * 262144;

    const int tid = threadIdx.x;
    const int wave = tid >> 6, lane = tid & 63;
    const int quad = lane >> 4, m16 = lane & 15;
    const int wr = wave >> 1, wc = wave & 1;
    const int row0 = by * 64, col0 = bx * 128;

    const int srowA = wave * 16 + (lane >> 2);
    const int srowB = wave * 32 + (lane >> 2);
    const int scol = (lane & 3) * 8;
    const _Float16* agp = A + (size_t)(row0 + srowA) * 512 + scol;
    const _Float16* bgp = Bp + (size_t)(col0 + srowB) * 512 + scol;
    const int ldsAoff = wave * 1024;
    const int ldsBoff = 4096 + wave * 2048;

    f32x4 acc[2][4];
#pragma unroll
    for (int mt = 0; mt < 2; ++mt)
#pragma unroll
        for (int nt = 0; nt < 4; ++nt) acc[mt][nt] = (f32x4){0.f, 0.f, 0.f, 0.f};

    auto stage = [&](int i, int buf) {
        char* base = smem + buf * 12288;
        const int k0 = i * 32;
        glds16(agp + k0, base + ldsAoff);
#pragma unroll
        for (int j = 0; j < 2; ++j)
            glds16(bgp + k0 + j * 16 * 512, base + ldsBoff + j * 1024);
    };

    stage(0, 0);
    for (int i = 0; i < 16; ++i) {
        __syncthreads();
        if (i + 1 < 16) stage(i + 1, (i + 1) & 1);
        const char* bb = smem + (i & 1) * 12288;
        const char* pa = bb + (wr * 32 + m16) * 64 + quad * 16;
        const char* pb = bb + 4096 + (wc * 64 + m16) * 64 + quad * 16;
        f16x8 af[2];
#pragma unroll
        for (int mt = 0; mt < 2; ++mt) af[mt] = *(const f16x8*)(pa + mt * 1024);
#pragma unroll
        for (int nt = 0; nt < 4; ++nt) {
            f16x8 bf = *(const f16x8*)(pb + nt * 1024);
#pragma unroll
            for (int mt = 0; mt < 2; ++mt) acc[mt][nt] = MFMA16(af[mt], bf, acc[mt][nt]);
        }
    }

    if (seg < 2) {
        _Float16* o = seg == 0 ? qh : kh;
#pragma unroll
        for (int mt = 0; mt < 2; ++mt)
#pragma unroll
            for (int nt = 0; nt < 4; ++nt)
#pragma unroll
                for (int rr = 0; rr < 4; ++rr) {
                    int row = row0 + wr * 32 + mt * 16 + quad * 4 + rr;
                    int col = col0 + wc * 64 + nt * 16 + m16;
                    o[(size_t)row * 512 + col] = (_Float16)acc[mt][nt][rr];
                }
    } else {
        __syncthreads();
        char* reg = smem + wave * 4096;
#pragma unroll
        for (int nt = 0; nt < 4; ++nt)
#pragma unroll
            for (int mt = 0; mt < 2; ++mt) {
                f16x4 pk;
#pragma unroll
                for (int rr = 0; rr < 4; ++rr) pk[rr] = (_Float16)acc[mt][nt][rr];
                *(f16x4*)(reg + (nt * 16 + m16) * 64 + (mt * 16 + quad * 4) * 2) = pk;
            }
        const int b = row0 >> 11;
        const int s_base = (row0 & 2047) + wr * 32;
        const int u_base = col0 + wc * 64;
#pragma unroll
        for (int j = 0; j < 4; ++j) {
            int n = j * 16 + (lane >> 2);
            int mo = (lane & 3) * 8;
            f16x8 val = *(const f16x8*)(reg + n * 64 + mo * 2);
            *(f16x8*)(vt + (size_t)(b * 512 + u_base + n) * 2048 + s_base + mo) = val;
        }
    }
}

// Score GEMM, 128x128 tiles, batch-pinned: b = blockIdx.x (1024 blocks),
// z = b&7 (XCD), r = b>>3: y = r>>4 (q-tile), x = r&15 (s-tile).
__global__ __launch_bounds__(256) void score_kernel(
    const _Float16* __restrict__ qh, const _Float16* __restrict__ kh,
    float* __restrict__ S) {
    __shared__ __align__(16) char smem[32768];
    const int b = blockIdx.x;
    const int z = b & 7, r = b >> 3;
    const int by = r >> 4, bx = r & 15;
    const int tid = threadIdx.x;
    const int wave = tid >> 6, lane = tid & 63;
    const int quad = lane >> 4, m16 = lane & 15;
    const int wr = wave >> 1, wc = wave & 1;
    const int row0 = z * 1024 + by * 128;
    const int col0 = bx * 128;

    const int srow = wave * 32 + (lane >> 2);
    const int scol = (lane & 3) * 8;
    const _Float16* agp = qh + (size_t)(row0 + srow) * 512 + scol;
    const _Float16* bgp = kh + (size_t)(z * 2048 + col0 + srow) * 512 + scol;
    const int ldsAoff = wave * 2048;
    const int ldsBoff = 8192 + wave * 2048;

    f32x4 acc[4][4];
#pragma unroll
    for (int mt = 0; mt < 4; ++mt)
#pragma unroll
        for (int nt = 0; nt < 4; ++nt) acc[mt][nt] = (f32x4){0.f, 0.f, 0.f, 0.f};

    auto stage = [&](int i, int buf) {
        char* base = smem + buf * 16384;
        const int k0 = i * 32;
#pragma unroll
        for (int j = 0; j < 2; ++j) {
            glds16(agp + k0 + j * 16 * 512, base + ldsAoff + j * 1024);
            glds16(bgp + k0 + j * 16 * 512, base + ldsBoff + j * 1024);
        }
    };

    stage(0, 0);
    for (int i = 0; i < 16; ++i) {
        __syncthreads();
        if (i + 1 < 16) stage(i + 1, (i + 1) & 1);
        const char* bb = smem + (i & 1) * 16384;
        const char* pa = bb + (wr * 64 + m16) * 64 + quad * 16;
        const char* pb = bb + 8192 + (wc * 64 + m16) * 64 + quad * 16;
        f16x8 af[4];
#pragma unroll
        for (int mt = 0; mt < 4; ++mt) af[mt] = *(const f16x8*)(pa + mt * 1024);
#pragma unroll
        for (int nt = 0; nt < 4; ++nt) {
            f16x8 bf = *(const f16x8*)(pb + nt * 1024);
#pragma unroll
            for (int mt = 0; mt < 4; ++mt) acc[mt][nt] = MFMA16(af[mt], bf, acc[mt][nt]);
        }
    }
#pragma unroll
    for (int mt = 0; mt < 4; ++mt)
#pragma unroll
        for (int nt = 0; nt < 4; ++nt)
#pragma unroll
            for (int rr = 0; rr < 4; ++rr) {
                int row = row0 + wr * 64 + mt * 16 + quad * 4 + rr;
                int col = col0 + wc * 64 + nt * 16 + m16;
                S[(size_t)row * 2048 + col] = acc[mt][nt][rr];
            }
}

// Row softmax over 2048 cols, fp32 in -> fp16 out (normalized). One block/row.
__global__ __launch_bounds__(256) void softmax_kernel(const float* __restrict__ S,
                                                      _Float16* __restrict__ P) {
    const int row = blockIdx.x;
    const int tid = threadIdx.x;
    const int wave = tid >> 6, lane = tid & 63;
    __shared__ float red[8];

    const float* sp = S + (size_t)row * 2048 + tid * 8;
    float4 x0 = *(const float4*)sp;
    float4 x1 = *(const float4*)(sp + 4);
    float v[8] = {x0.x, x0.y, x0.z, x0.w, x1.x, x1.y, x1.z, x1.w};

    float mx = v[0];
#pragma unroll
    for (int i = 1; i < 8; ++i) mx = fmaxf(mx, v[i]);
#pragma unroll
    for (int off = 32; off > 0; off >>= 1) mx = fmaxf(mx, __shfl_down(mx, off));
    if (lane == 0) red[wave] = mx;
    __syncthreads();
    if (tid == 0) red[4] = fmaxf(fmaxf(red[0], red[1]), fmaxf(red[2], red[3]));
    __syncthreads();
    mx = red[4];

    float e[8];
    float sum = 0.f;
#pragma unroll
    for (int i = 0; i < 8; ++i) {
        e[i] = exp2f((v[i] - mx) * L2E);
        sum += e[i];
    }
#pragma unroll
    for (int off = 32; off > 0; off >>= 1) sum += __shfl_down(sum, off);
    if (lane == 0) red[wave] = sum;
    __syncthreads();
    if (tid == 0) red[5] = red[0] + red[1] + red[2] + red[3];
    __syncthreads();
    float inv = 1.0f / red[5];

    f16x8 ov;
#pragma unroll
    for (int i = 0; i < 8; ++i) ov[i] = (_Float16)(e[i] * inv);
    *(f16x8*)(P + (size_t)row * 2048 + tid * 8) = ov;
}

// PV GEMM, 64 q x 128 u tiles, batch-pinned: b = blockIdx.x (512 blocks),
// z = b&7 (XCD -> vt[z] 2 MB stays L2-resident), r = b>>3: y = r>>2 (q-tile,
// outer so P streams in 256 KB slabs), x = r&3 (u-slab).
__global__ __launch_bounds__(256) void pv_kernel(
    const _Float16* __restrict__ P, const _Float16* __restrict__ vt,
    float* __restrict__ out) {
    __shared__ __align__(16) char smem[24576];
    const int b = blockIdx.x;
    const int z = b & 7, r = b >> 3;
    const int by = r >> 2, bx = r & 3;
    const int tid = threadIdx.x;
    const int wave = tid >> 6, lane = tid & 63;
    const int quad = lane >> 4, m16 = lane & 15;
    const int wr = wave >> 1, wc = wave & 1;
    const int row0 = z * 1024 + by * 64;
    const int col0 = bx * 128;

    const int srowA = wave * 16 + (lane >> 2);
    const int srowB = wave * 32 + (lane >> 2);
    const int scol = (lane & 3) * 8;
    const _Float16* agp = P + (size_t)(row0 + srowA) * 2048 + scol;
    const _Float16* bgp = vt + (size_t)(z * 512 + col0 + srowB) * 2048 + scol;
    const int ldsAoff = wave * 1024;
    const int ldsBoff = 4096 + wave * 2048;

    f32x4 acc[2][4];
#pragma unroll
    for (int mt = 0; mt < 2; ++mt)
#pragma unroll
        for (int nt = 0; nt < 4; ++nt) acc[mt][nt] = (f32x4){0.f, 0.f, 0.f, 0.f};

    auto stage = [&](int i, int buf) {
        char* base = smem + buf * 12288;
        const int k0 = i * 32;
        glds16(agp + k0, base + ldsAoff);
#pragma unroll
        for (int j = 0; j < 2; ++j)
            glds16(bgp + k0 + j * 16 * 2048, base + ldsBoff + j * 1024);
    };

    stage(0, 0);
    for (int i = 0; i < 64; ++i) {
        __syncthreads();
        if (i + 1 < 64) stage(i + 1, (i + 1) & 1);
        const char* bb = smem + (i & 1) * 12288;
        const char* pa = bb + (wr * 32 + m16) * 64 + quad * 16;
        const char* pb = bb + 4096 + (wc * 64 + m16) * 64 + quad * 16;
        f16x8 af[2];
#pragma unroll
        for (int mt = 0; mt < 2; ++mt) af[mt] = *(const f16x8*)(pa + mt * 1024);
#pragma unroll
        for (int nt = 0; nt < 4; ++nt) {
            f16x8 bf = *(const f16x8*)(pb + nt * 1024);
#pragma unroll
            for (int mt = 0; mt < 2; ++mt) acc[mt][nt] = MFMA16(af[mt], bf, acc[mt][nt]);
        }
    }

#pragma unroll
    for (int mt = 0; mt < 2; ++mt)
#pragma unroll
        for (int nt = 0; nt < 4; ++nt)
#pragma unroll
            for (int rr = 0; rr < 4; ++rr) {
                int row = row0 + wr * 32 + mt * 16 + quad * 4 + rr;
                int col = col0 + wc * 64 + nt * 16 + m16;
                out[(size_t)row * 512 + col] = acc[mt][nt][rr];
            }
}

extern "C" void kernel_launch(void* const* d_in, const int* in_sizes, int n_in,
                              void* d_out, int out_size, void* d_ws, size_t ws_size,
                              hipStream_t stream) {
    const float* enc = (const float*)d_in[0];  // [8,2048,512]
    const float* dec = (const float*)d_in[1];  // [8,1024,512]
    const float* Wq = (const float*)d_in[2];   // [512,512]
    const float* Wk = (const float*)d_in[3];
    const float* Wv = (const float*)d_in[4];
    float* out = (float*)d_out;                // [8,1024,512] fp32

    char* ws = (char*)d_ws;
    _Float16* qh = (_Float16*)(ws);
    _Float16* kh = (_Float16*)(ws + ((size_t)8 << 20));
    _Float16* P = (_Float16*)(ws);                          // aliases qh/kh after score
    _Float16* vt = (_Float16*)(ws + ((size_t)32 << 20));
    float* S = (float*)(ws + ((size_t)48 << 20));
    _Float16* dech = (_Float16*)(ws + ((size_t)48 << 20));  // dead before S written
    _Float16* wts = (_Float16*)(ws + ((size_t)56 << 20));   // dead before S written
    _Float16* ench = (_Float16*)(ws + ((size_t)112 << 20)); // dead after proj

    dim3 blk(256);
    prep_kernel<<<6336, blk, 0, stream>>>(enc, dec, Wq, Wk, Wv, ench, dech, wts);
    proj_kernel<<<2560, blk, 0, stream>>>(dech, ench, wts, qh, kh, vt);
    score_kernel<<<1024, blk, 0, stream>>>(qh, kh, S);
    softmax_kernel<<<8192, blk, 0, stream>>>(S, P);
    pv_kernel<<<512, blk, 0, stream>>>(P, vt, out);
}